// Round 1
// 491.058 us; speedup vs baseline: 1.1578x; 1.1578x over previous
//
#include <hip/hip_runtime.h>
#include <hip/hip_fp16.h>

// Problem constants
#define OUT_F 4096
#define IN_F  4096
#define M_TOTAL 8192          // 4 * 2048
#define TOTAL_W (OUT_F * IN_F)

typedef _Float16 f16x8 __attribute__((ext_vector_type(8)));
typedef float    f32x4 __attribute__((ext_vector_type(4)));

__device__ const float NF4_LUT_C[16] = {
    -1.0f, -0.6961928009986877f, -0.5250730514526367f, -0.39491748809814453f,
    -0.28444138169288635f, -0.18477343022823334f, -0.09105003625154495f, 0.0f,
    0.07958029955625534f, 0.16093020141124725f, 0.24611230194568634f,
    0.33791524171829224f, 0.44070982933044434f, 0.5626170039176941f,
    0.7229568362236023f, 1.0f};

// ---------------- Dequant: indices + q_scales -> W fp16 [OUT_F][IN_F] ----------------
__global__ __launch_bounds__(256) void k_dequant(const int* __restrict__ idx,
                                                 const int* __restrict__ qs,
                                                 _Float16* __restrict__ W) {
    __shared__ float slut[16];
    if (threadIdx.x < 16) slut[threadIdx.x] = NF4_LUT_C[threadIdx.x];
    __syncthreads();
    int t = blockIdx.x * 256 + threadIdx.x;              // 0 .. TOTAL_W/8-1
    const int4* ip = (const int4*)idx;
    int4 a = ip[2 * t];
    int4 b = ip[2 * t + 1];
    // exact reference order: (q/127)*0.05 in fp32, then vals*absmax, then fp16 cast
    float absmax = ((float)qs[t >> 3] / 127.0f) * 0.05f;
    f16x8 o;
    o[0] = (_Float16)(slut[a.x] * absmax);
    o[1] = (_Float16)(slut[a.y] * absmax);
    o[2] = (_Float16)(slut[a.z] * absmax);
    o[3] = (_Float16)(slut[a.w] * absmax);
    o[4] = (_Float16)(slut[b.x] * absmax);
    o[5] = (_Float16)(slut[b.y] * absmax);
    o[6] = (_Float16)(slut[b.z] * absmax);
    o[7] = (_Float16)(slut[b.w] * absmax);
    *(f16x8*)(W + (size_t)t * 8) = o;
}

// ---------------- Cast X fp32 -> fp16 ----------------
__global__ __launch_bounds__(256) void k_cast(const float* __restrict__ x,
                                              _Float16* __restrict__ xh) {
    int t = blockIdx.x * 256 + threadIdx.x;              // 8 elems per thread
    const float4* xp = (const float4*)x;
    float4 a = xp[2 * t];
    float4 b = xp[2 * t + 1];
    f16x8 o;
    o[0] = (_Float16)a.x; o[1] = (_Float16)a.y; o[2] = (_Float16)a.z; o[3] = (_Float16)a.w;
    o[4] = (_Float16)b.x; o[5] = (_Float16)b.y; o[6] = (_Float16)b.z; o[7] = (_Float16)b.w;
    *(f16x8*)(xh + (size_t)t * 8) = o;
}

// ---------------- GEMM: C[M][N] = A[M][K] * B[N][K]^T ----------------
// 256x256 tile, BK=64, 512 threads = 8 waves (2M x 4N), per-wave 128x64 out
// via 8x4 frags of mfma_f32_16x16x32_f16 (2 k-steps per BK).
//
// 8-phase-class schedule (4 phases per K-tile, 2 K-tiles per buffer cycle):
//   ph1: ds_read A(m0-3,k0-1)+B(n0-1,k0-1); bar; lgkm0; prio1; 16 MFMA; prio0; bar
//   ph2: ds_read B(n2-3);                   bar; lgkm0; prio1; 16 MFMA; prio0; bar
//   ph3: ds_read A(m4-7); STAGE B(t+2)  [B regions of this buf dead after ph2 bar]
//                                           bar; lgkm0; prio1; 16 MFMA; prio0; bar
//   ph4: STAGE A(t+2)                   [A regions dead after ph3 bar]
//        prio1; 16 MFMA; prio0; vmcnt(8); bar
// Counted vmcnt: tile t+1 (8 loads, issued iter t-1) completes at iter-t end while
// tile t+2's 8 loads stay in flight across the barrier. Never vmcnt(0) except the
// tail (t==NT-2). Tile t+2 lands in the SAME buffer as tile t, strictly after the
// region death points above -> 2 LDS buffers suffice for ~2-tile prefetch depth.
//
// LDS swizzle: 16B chunk (row r, kchunk c) -> physical r*8 + (c ^ (r&7)).
// global_load_lds dest stays lane-linear; the GLOBAL k-offset is pre-swizzled
// (kc = (t&7)^((t>>3)&7), j-invariant). Read side: frag row = base + (lane&15),
// chunk = kstep*4 + (lane>>4), phys pos = chunk ^ (lane&7) -> each 16B slot gets
// 8 lanes / 8-cycle b128 service, balanced (2-way same-bank pairs are free).

__device__ __forceinline__ void async16(const _Float16* g, _Float16* l) {
    __builtin_amdgcn_global_load_lds(
        (const __attribute__((address_space(1))) void*)g,
        (__attribute__((address_space(3))) void*)l,
        16, 0, 0);
}

#define MFMA16(a, b, c) __builtin_amdgcn_mfma_f32_16x16x32_f16(a, b, c, 0, 0, 0)
#define BAR()   __builtin_amdgcn_s_barrier()
#define LGKM0() asm volatile("s_waitcnt lgkmcnt(0)" ::: "memory")

#define TILE_E (256 * 64)

__global__ __launch_bounds__(512, 2) void k_gemm(const _Float16* __restrict__ A,
                                                 const _Float16* __restrict__ B,
                                                 float* __restrict__ C) {
    const int K = IN_F, N = OUT_F;
    __shared__ __align__(1024) _Float16 sA[2][TILE_E];   // 64 KiB
    __shared__ __align__(1024) _Float16 sB[2][TILE_E];   // 64 KiB

    const int tid = threadIdx.x;
    // Raster: 32 groups of 16 blocks (4 bm x 4 bn) over 32x16 tile grid (L2 reuse).
    const int bid = blockIdx.x;            // 0..511
    const int g   = bid >> 4;              // 0..31
    const int wv  = bid & 15;
    const int gy  = g >> 2;                // 0..7
    const int gx  = g & 3;                 // 0..3
    const int m0  = (gy * 4 + (wv >> 2)) * 256;
    const int n0  = (gx * 4 + (wv & 3)) * 256;

    const int lane = tid & 63;
    const int wave = tid >> 6;
    const int wm   = (wave >> 2) * 128;    // 0 or 128
    const int wn   = (wave & 3) * 64;      // 0,64,128,192

    // Fragment read addressing (16x16x32: row/col = lane&15, k-chunk = lane>>4)
    const int fr   = lane & 15;
    const int fk   = lane >> 4;
    const int sw   = fr & 7;
    const int aRow = (wm + fr) * 64;       // element offset of frag row base
    const int bRow = (wn + fr) * 64;
    const int p0   = ((0 * 4 + fk) ^ sw) * 8;   // kstep 0 phys offset (elems)
    const int p1   = ((1 * 4 + fk) ^ sw) * 8;   // kstep 1

    // Staging: pass j covers phys chunks [j*512, j*512+512): thread t -> chunk j*512+t,
    // row = j*64 + (t>>3), pos = t&7, global kchunk = pos ^ (row&7) (j-invariant).
    const int rr  = tid >> 3;                              // 0..63
    const int kc  = ((tid & 7) ^ (rr & 7)) * 8;            // global k elem offset
    const _Float16* agp = A + (size_t)(m0 + rr) * K + kc;
    const _Float16* bgp = B + (size_t)(n0 + rr) * K + kc;
    const int dOff = tid * 8;                              // LDS dest elem offset base

    f32x4 acc[8][4];
#pragma unroll
    for (int mi = 0; mi < 8; ++mi)
#pragma unroll
        for (int ni = 0; ni < 4; ++ni)
#pragma unroll
            for (int r = 0; r < 4; ++r) acc[mi][ni][r] = 0.f;

    // ---- prologue: stage tiles 0 (buf0) and 1 (buf1); tile1 stays in flight ----
#pragma unroll
    for (int j = 0; j < 4; ++j) async16(agp + (size_t)j * 64 * K,       &sA[0][j * 4096 + dOff]);
#pragma unroll
    for (int j = 0; j < 4; ++j) async16(bgp + (size_t)j * 64 * K,       &sB[0][j * 4096 + dOff]);
#pragma unroll
    for (int j = 0; j < 4; ++j) async16(agp + (size_t)j * 64 * K + 64,  &sA[1][j * 4096 + dOff]);
#pragma unroll
    for (int j = 0; j < 4; ++j) async16(bgp + (size_t)j * 64 * K + 64,  &sB[1][j * 4096 + dOff]);
    asm volatile("s_waitcnt vmcnt(8)" ::: "memory");   // tile0 landed, tile1 in flight
    BAR();

    const int NT = K / 64;   // 64
    f16x8 af[4][2], bf[4][2];

#pragma unroll 2
    for (int t = 0; t < NT; ++t) {
        const _Float16* sAb = sA[t & 1];
        const _Float16* sBb = sB[t & 1];
        _Float16* dA = sA[t & 1];          // tile t+2 shares this buffer
        _Float16* dB = sB[t & 1];
        const bool st = (t + 2 < NT);
        const int ktn = (t + 2) * 64;

        // ---------- phase 1: A m0-3, B n0-1 ----------
#pragma unroll
        for (int mi = 0; mi < 4; ++mi) {
            af[mi][0] = *(const f16x8*)(sAb + aRow + mi * 1024 + p0);
            af[mi][1] = *(const f16x8*)(sAb + aRow + mi * 1024 + p1);
        }
#pragma unroll
        for (int ni = 0; ni < 2; ++ni) {
            bf[ni][0] = *(const f16x8*)(sBb + bRow + ni * 1024 + p0);
            bf[ni][1] = *(const f16x8*)(sBb + bRow + ni * 1024 + p1);
        }
        BAR();
        LGKM0();
        __builtin_amdgcn_s_setprio(1);
#pragma unroll
        for (int mi = 0; mi < 4; ++mi)
#pragma unroll
            for (int ni = 0; ni < 2; ++ni) {
                acc[mi][ni] = MFMA16(af[mi][0], bf[ni][0], acc[mi][ni]);
                acc[mi][ni] = MFMA16(af[mi][1], bf[ni][1], acc[mi][ni]);
            }
        __builtin_amdgcn_s_setprio(0);
        BAR();

        // ---------- phase 2: B n2-3 ----------
#pragma unroll
        for (int ni = 2; ni < 4; ++ni) {
            bf[ni][0] = *(const f16x8*)(sBb + bRow + ni * 1024 + p0);
            bf[ni][1] = *(const f16x8*)(sBb + bRow + ni * 1024 + p1);
        }
        BAR();
        LGKM0();
        __builtin_amdgcn_s_setprio(1);
#pragma unroll
        for (int mi = 0; mi < 4; ++mi)
#pragma unroll
            for (int ni = 2; ni < 4; ++ni) {
                acc[mi][ni] = MFMA16(af[mi][0], bf[ni][0], acc[mi][ni]);
                acc[mi][ni] = MFMA16(af[mi][1], bf[ni][1], acc[mi][ni]);
            }
        __builtin_amdgcn_s_setprio(0);
        BAR();

        // ---------- phase 3: A m4-7 (reuse af regs); stage B(t+2) ----------
#pragma unroll
        for (int mi = 0; mi < 4; ++mi) {
            af[mi][0] = *(const f16x8*)(sAb + aRow + 4096 + mi * 1024 + p0);
            af[mi][1] = *(const f16x8*)(sAb + aRow + 4096 + mi * 1024 + p1);
        }
        if (st) {
#pragma unroll
            for (int j = 0; j < 4; ++j)
                async16(bgp + (size_t)j * 64 * K + ktn, &dB[j * 4096 + dOff]);
        }
        BAR();
        LGKM0();
        __builtin_amdgcn_s_setprio(1);
#pragma unroll
        for (int mi = 0; mi < 4; ++mi)
#pragma unroll
            for (int ni = 0; ni < 2; ++ni) {
                acc[mi + 4][ni] = MFMA16(af[mi][0], bf[ni][0], acc[mi + 4][ni]);
                acc[mi + 4][ni] = MFMA16(af[mi][1], bf[ni][1], acc[mi + 4][ni]);
            }
        __builtin_amdgcn_s_setprio(0);
        BAR();

        // ---------- phase 4: stage A(t+2); counted vmcnt ----------
        if (st) {
#pragma unroll
            for (int j = 0; j < 4; ++j)
                async16(agp + (size_t)j * 64 * K + ktn, &dA[j * 4096 + dOff]);
        }
        __builtin_amdgcn_s_setprio(1);
#pragma unroll
        for (int mi = 0; mi < 4; ++mi)
#pragma unroll
            for (int ni = 2; ni < 4; ++ni) {
                acc[mi + 4][ni] = MFMA16(af[mi][0], bf[ni][0], acc[mi + 4][ni]);
                acc[mi + 4][ni] = MFMA16(af[mi][1], bf[ni][1], acc[mi + 4][ni]);
            }
        __builtin_amdgcn_s_setprio(0);
        if (t < NT - 2) {
            asm volatile("s_waitcnt vmcnt(8)" ::: "memory");  // tile t+1 landed, t+2 in flight
        } else if (t == NT - 2) {
            asm volatile("s_waitcnt vmcnt(0)" ::: "memory");  // drain for last tile
        }
        if (t < NT - 1) BAR();
    }

    // Epilogue: 16x16x32 C/D layout col=lane&15, row=(lane>>4)*4+reg
    const int crow0 = m0 + wm + (lane >> 4) * 4;
    const int ccol0 = n0 + wn + (lane & 15);
#pragma unroll
    for (int mi = 0; mi < 8; ++mi)
#pragma unroll
        for (int ni = 0; ni < 4; ++ni)
#pragma unroll
            for (int r = 0; r < 4; ++r)
                C[(size_t)(crow0 + mi * 16 + r) * N + ccol0 + ni * 16] = acc[mi][ni][r];
}

extern "C" void kernel_launch(void* const* d_in, const int* in_sizes, int n_in,
                              void* d_out, int out_size, void* d_ws, size_t ws_size,
                              hipStream_t stream) {
    const float* x       = (const float*)d_in[0];
    const int*   indices = (const int*)d_in[1];
    const int*   qscales = (const int*)d_in[2];
    float*       out     = (float*)d_out;

    _Float16* W  = (_Float16*)d_ws;                                   // 32 MiB
    _Float16* Xh = (_Float16*)((char*)d_ws + (size_t)TOTAL_W * 2);    // 64 MiB

    k_dequant<<<TOTAL_W / 8 / 256, 256, 0, stream>>>(indices, qscales, W);
    k_cast<<<(size_t)M_TOTAL * IN_F / 8 / 256, 256, 0, stream>>>(x, Xh);

    k_gemm<<<512, 512, 0, stream>>>(Xh, W, out);
}